// Round 9
// baseline (456.895 us; speedup 1.0000x reference)
//
#include <hip/hip_runtime.h>
#include <math.h>

#define N_NODES 50000
#define N_EDGES 800000
#define NFEAT 512
#define NHID 256
#define NCODE 64
#define NCLASS 40
#define NCLS_PAD 48
#define NB_SCAN 196  // ceil(50000/256)

typedef __attribute__((ext_vector_type(8))) short short8;
typedef __attribute__((ext_vector_type(8))) unsigned short ushort8;
typedef __attribute__((ext_vector_type(4))) unsigned short ushort4v;
typedef __attribute__((ext_vector_type(4))) float floatx4;

__device__ inline unsigned short f2bf(float f) {
    unsigned u = __builtin_bit_cast(unsigned, f);
    u += 0x7fff + ((u >> 16) & 1);
    return (unsigned short)(u >> 16);
}
__device__ inline float bf2f(unsigned short h) {
    return __builtin_bit_cast(float, (unsigned)h << 16);
}
// packed fp32->bf16 (RNE), 2 elems/instr
__device__ inline unsigned pkbf(float lo, float hi) {
    unsigned r;
    asm("v_cvt_pk_bf16_f32 %0, %1, %2" : "=v"(r) : "v"(lo), "v"(hi));
    return r;
}
// async global->LDS 16B DMA (dest = wave-uniform base + lane*16)
__device__ inline void gload_lds16(const void* g, void* l) {
    __builtin_amdgcn_global_load_lds(
        (const __attribute__((address_space(1))) unsigned int*)g,
        (__attribute__((address_space(3))) unsigned int*)l, 16, 0, 0);
}

// ---------------- CSR build (by dst) ----------------
__global__ __launch_bounds__(256) void hist_kernel(const int* __restrict__ dst,
                                                   int* __restrict__ counts) {
    int t = blockIdx.x * 256 + threadIdx.x;
    if (t < N_EDGES) atomicAdd(&counts[dst[t]], 1);
}

// 3-phase device scan
__global__ __launch_bounds__(256) void scan_block_sums(const int* __restrict__ counts,
                                                       int* __restrict__ blockSums) {
    __shared__ int red[256];
    int t = threadIdx.x;
    int i = blockIdx.x * 256 + t;
    red[t] = (i < N_NODES) ? counts[i] : 0;
    __syncthreads();
#pragma unroll
    for (int off = 128; off > 0; off >>= 1) {
        if (t < off) red[t] += red[t + off];
        __syncthreads();
    }
    if (t == 0) blockSums[blockIdx.x] = red[0];
}

__global__ __launch_bounds__(256) void scan_block_offsets(const int* __restrict__ blockSums,
                                                          int* __restrict__ blockOffsets,
                                                          int* __restrict__ offsets) {
    __shared__ int s[256];
    int t = threadIdx.x;
    int v = (t < NB_SCAN) ? blockSums[t] : 0;
    s[t] = v;
    __syncthreads();
#pragma unroll
    for (int off = 1; off < 256; off <<= 1) {
        int x = (t >= off) ? s[t - off] : 0;
        __syncthreads();
        s[t] += x;
        __syncthreads();
    }
    if (t < NB_SCAN) blockOffsets[t] = s[t] - v;  // exclusive
    if (t == 255) offsets[N_NODES] = s[255];      // total = E
}

__global__ __launch_bounds__(256) void scan_final(const int* __restrict__ counts,
                                                  const int* __restrict__ blockOffsets,
                                                  int* __restrict__ offsets) {
    __shared__ int s[256];
    int t = threadIdx.x;
    int i = blockIdx.x * 256 + t;
    int v = (i < N_NODES) ? counts[i] : 0;
    s[t] = v;
    __syncthreads();
#pragma unroll
    for (int off = 1; off < 256; off <<= 1) {
        int x = (t >= off) ? s[t - off] : 0;
        __syncthreads();
        s[t] += x;
        __syncthreads();
    }
    if (i < N_NODES) offsets[i] = blockOffsets[blockIdx.x] + s[t] - v;  // exclusive
}

// scatter edges into dst-sorted order as packed (src, w_bits) int2
__global__ __launch_bounds__(256) void scatter_kernel(const int* __restrict__ dst,
                                                      const int* __restrict__ src,
                                                      const float* __restrict__ w,
                                                      const int* __restrict__ offsets,
                                                      int* __restrict__ cursor,
                                                      int2* __restrict__ edges) {
    int t = blockIdx.x * 256 + threadIdx.x;
    if (t < N_EDGES) {
        int d = dst[t];
        int pos = offsets[d] + atomicAdd(&cursor[d], 1);
        edges[pos] = make_int2(src[t], __builtin_bit_cast(int, w[t]));
    }
}

// ---------------- Fused weight prep: W1t / W2bt / W_mulvt / W_dect ----------------
__global__ __launch_bounds__(256) void wprep_kernel(const float* __restrict__ W1,
                                                    const float* __restrict__ W2,
                                                    const float* __restrict__ W_mu,
                                                    const float* __restrict__ W_lv,
                                                    const float* __restrict__ W_dec,
                                                    unsigned short* __restrict__ W1t,
                                                    unsigned short* __restrict__ W2bt,
                                                    unsigned short* __restrict__ W_mulvt,
                                                    unsigned short* __restrict__ W_dect) {
    int idx = blockIdx.x * 256 + threadIdx.x;
    if (idx < NFEAT * NHID) {
        int k = idx >> 8;
        int n = idx & 255;
        W1t[(size_t)n * NFEAT + k] = f2bf(W1[idx]);
    } else if (idx < NFEAT * NHID + NCLS_PAD * NFEAT) {
        int i2 = idx - NFEAT * NHID;
        int n = i2 >> 9;
        int k = i2 & 511;
        W2bt[i2] = (n < NCLASS) ? f2bf(W2[(size_t)k * NCLASS + n]) : (unsigned short)0;
    } else if (idx < NFEAT * NHID + NCLS_PAD * NFEAT + 128 * 256) {
        int i2 = idx - NFEAT * NHID - NCLS_PAD * NFEAT;
        int j = i2 >> 8;
        int k = i2 & 255;
        float v = (j < 64) ? W_mu[(size_t)k * NCODE + j] : W_lv[(size_t)k * NCODE + (j - 64)];
        W_mulvt[i2] = f2bf(v);
    } else if (idx < NFEAT * NHID + NCLS_PAD * NFEAT + 128 * 256 + 256 * 64) {
        int i2 = idx - NFEAT * NHID - NCLS_PAD * NFEAT - 128 * 256;
        int n = i2 >> 6;
        int k = i2 & 63;
        W_dect[i2] = f2bf(W_dec[(size_t)k * NHID + n]);
    }
}

// ---------------- GEMM1 v3: 128x128 tile, BK=64, single-buffer, XOR-swizzled, A reg-prefetch
__global__ __launch_bounds__(256) void gemm1_mfma(const float* __restrict__ A,
                                                  const unsigned short* __restrict__ Bt,
                                                  unsigned short* __restrict__ C) {
    __shared__ unsigned short As[128 * 64];
    __shared__ unsigned short Bs[128 * 64];
    int t = threadIdx.x;
    int wave = t >> 6, lane = t & 63;
    int quad = lane >> 4, m16 = lane & 15;
    int wr = wave >> 1, wc = wave & 1;
    int m0 = blockIdx.x * 128;
    int n0 = blockIdx.y * 128;

    int srow = t >> 3;
    int kcs = (t & 7) ^ (srow & 7);  // swizzled source chunk
    const float* Ap[4];
#pragma unroll
    for (int r = 0; r < 4; ++r) {
        int ga = m0 + r * 32 + srow;
        if (ga >= N_NODES) ga = N_NODES - 1;
        Ap[r] = A + (size_t)ga * NFEAT + kcs * 8;
    }
    const unsigned short* Bbase = Bt + (size_t)(n0 + srow) * NFEAT + kcs * 8;

    floatx4 acc[4][4];
#pragma unroll
    for (int m = 0; m < 4; ++m)
#pragma unroll
        for (int n = 0; n < 4; ++n) acc[m][n] = (floatx4){0.f, 0.f, 0.f, 0.f};

    float4 a0[4], a1[4];
#pragma unroll
    for (int r = 0; r < 4; ++r) {
        a0[r] = *(const float4*)(Ap[r]);
        a1[r] = *(const float4*)(Ap[r] + 4);
    }

#pragma unroll
    for (int k0 = 0; k0 < NFEAT; k0 += 64) {
        uint4 aw[4];
#pragma unroll
        for (int r = 0; r < 4; ++r) {
            aw[r].x = pkbf(a0[r].x, a0[r].y);
            aw[r].y = pkbf(a0[r].z, a0[r].w);
            aw[r].z = pkbf(a1[r].x, a1[r].y);
            aw[r].w = pkbf(a1[r].z, a1[r].w);
        }
        __syncthreads();
#pragma unroll
        for (int r = 0; r < 4; ++r)
            gload_lds16(Bbase + (size_t)r * 32 * NFEAT + k0, &Bs[(r * 256 + wave * 64) * 8]);
#pragma unroll
        for (int r = 0; r < 4; ++r) *(uint4*)&As[(r * 256 + t) * 8] = aw[r];
        __syncthreads();
        if (k0 + 64 < NFEAT) {
#pragma unroll
            for (int r = 0; r < 4; ++r) {
                a0[r] = *(const float4*)(Ap[r] + k0 + 64);
                a1[r] = *(const float4*)(Ap[r] + k0 + 68);
            }
        }
#pragma unroll
        for (int c = 0; c < 2; ++c) {
            int sw = ((c * 4 + quad) ^ (m16 & 7)) * 8;
            short8 af[4], bfr[4];
#pragma unroll
            for (int m = 0; m < 4; ++m)
                af[m] = *(const short8*)&As[(wr * 64 + m * 16 + m16) * 64 + sw];
#pragma unroll
            for (int n = 0; n < 4; ++n)
                bfr[n] = *(const short8*)&Bs[(wc * 64 + n * 16 + m16) * 64 + sw];
#pragma unroll
            for (int m = 0; m < 4; ++m)
#pragma unroll
                for (int n = 0; n < 4; ++n)
                    acc[m][n] =
                        __builtin_amdgcn_mfma_f32_16x16x32_bf16(af[m], bfr[n], acc[m][n], 0, 0, 0);
        }
    }
#pragma unroll
    for (int m = 0; m < 4; ++m) {
#pragma unroll
        for (int n = 0; n < 4; ++n) {
            int col = n0 + wc * 64 + n * 16 + m16;
#pragma unroll
            for (int r = 0; r < 4; ++r) {
                int row = m0 + wr * 64 + m * 16 + quad * 4 + r;
                if (row < N_NODES) C[(size_t)row * NHID + col] = f2bf(acc[m][n][r]);
            }
        }
    }
}

// ---------------- SpMM1 v2: 2 edges/wave-step, 16B/lane gather ----------------
// Wave split into 2 halves; half h processes edge i+h with 32 lanes x ushort8 (16B) = 512B row.
// Halves merged via shfl_xor(32) at the end. VMEM instructions per edge halved vs v1.
__global__ __launch_bounds__(256) void spmm1_kernel(const int* __restrict__ offsets,
                                                    const int2* __restrict__ edges,
                                                    const unsigned short* __restrict__ S1b,
                                                    const float* __restrict__ b1,
                                                    unsigned short* __restrict__ x1cat) {
    int n = blockIdx.x * 4 + (threadIdx.x >> 6);
    int lane = threadIdx.x & 63;
    int h = lane >> 5;         // half index: which edge of the pair
    int l32 = lane & 31;       // 8-col chunk within the row
    int beg = offsets[n], end = offsets[n + 1];
    float acc[8];
#pragma unroll
    for (int j = 0; j < 8; ++j) acc[j] = 0.f;

    int i = beg;
    // main loop: 16 edges per iteration (8 per half), no clamps
    for (; i + 16 <= end; i += 16) {
        int2 e[8];
        ushort8 r[8];
#pragma unroll
        for (int u = 0; u < 8; ++u) e[u] = edges[i + u * 2 + h];
#pragma unroll
        for (int u = 0; u < 8; ++u)
            r[u] = *(const ushort8*)&S1b[(size_t)e[u].x * NHID + l32 * 8];
#pragma unroll
        for (int u = 0; u < 8; ++u) {
            float ww = __builtin_bit_cast(float, e[u].y);
#pragma unroll
            for (int j = 0; j < 8; ++j) acc[j] += ww * bf2f(r[u][j]);
        }
    }
    // tail: 2 edges per step, clamped
    for (; i < end; i += 2) {
        int idx = i + h;
        int ic = (idx < end) ? idx : (end - 1);
        int2 e = edges[ic];
        float ww = (idx < end) ? __builtin_bit_cast(float, e.y) : 0.f;
        ushort8 r = *(const ushort8*)&S1b[(size_t)e.x * NHID + l32 * 8];
#pragma unroll
        for (int j = 0; j < 8; ++j) acc[j] += ww * bf2f(r[j]);
    }
    // merge halves
#pragma unroll
    for (int j = 0; j < 8; ++j) acc[j] += __shfl_xor(acc[j], 32);
    // bias + relu + store (lanes 0..31 write 16B each)
    if (h == 0) {
        float4 b0 = *(const float4*)&b1[l32 * 8];
        float4 b4 = *(const float4*)&b1[l32 * 8 + 4];
        ushort8 hb;
        hb[0] = f2bf(fmaxf(acc[0] + b0.x, 0.f));
        hb[1] = f2bf(fmaxf(acc[1] + b0.y, 0.f));
        hb[2] = f2bf(fmaxf(acc[2] + b0.z, 0.f));
        hb[3] = f2bf(fmaxf(acc[3] + b0.w, 0.f));
        hb[4] = f2bf(fmaxf(acc[4] + b4.x, 0.f));
        hb[5] = f2bf(fmaxf(acc[5] + b4.y, 0.f));
        hb[6] = f2bf(fmaxf(acc[6] + b4.z, 0.f));
        hb[7] = f2bf(fmaxf(acc[7] + b4.w, 0.f));
        *(ushort8*)&x1cat[(size_t)n * (2 * NHID) + NHID + l32 * 8] = hb;
    }
}

// ---------------- MULV (gemm2-pattern): mulv[:,y*64..] = h1 @ W_mulvt[y-half] + bias --------
__global__ __launch_bounds__(256) void mulv_mfma(const unsigned short* __restrict__ x1cat,
                                                 const unsigned short* __restrict__ W_mulvt,
                                                 const float* __restrict__ b_mu,
                                                 const float* __restrict__ b_lv,
                                                 unsigned short* __restrict__ mulv) {
    __shared__ unsigned short Bs[64][264];  // 528B stride -> 2-way banks (free)
    int t = threadIdx.x;
    int wave = t >> 6, lane = t & 63;
    int quad = lane >> 4, m16 = lane & 15;
    int m0 = blockIdx.x * 64;
    int ybase = blockIdx.y * 64;

#pragma unroll
    for (int r = 0; r < 8; ++r) {
        int c = r * 256 + t;
        int row = c >> 5, col = (c & 31) * 8;
        *(ushort8*)&Bs[row][col] = *(const ushort8*)&W_mulvt[(size_t)(ybase + row) * 256 + col];
    }
    int arow = m0 + wave * 16 + m16;
    if (arow >= N_NODES) arow = N_NODES - 1;
    const unsigned short* Abase = x1cat + (size_t)arow * 512 + 256 + quad * 8;

    floatx4 acc[4];
#pragma unroll
    for (int i = 0; i < 4; ++i) acc[i] = (floatx4){0.f, 0.f, 0.f, 0.f};
    __syncthreads();

#pragma unroll
    for (int k0 = 0; k0 < 256; k0 += 32) {
        short8 af = *(const short8*)(Abase + k0);
#pragma unroll
        for (int nt = 0; nt < 4; ++nt) {
            short8 bfr = *(const short8*)&Bs[nt * 16 + m16][k0 + quad * 8];
            acc[nt] = __builtin_amdgcn_mfma_f32_16x16x32_bf16(af, bfr, acc[nt], 0, 0, 0);
        }
    }
    const float* bias_v = blockIdx.y ? b_lv : b_mu;
#pragma unroll
    for (int nt = 0; nt < 4; ++nt) {
        int j = nt * 16 + m16;
        float bias = bias_v[j];
#pragma unroll
        for (int r = 0; r < 4; ++r) {
            int row = m0 + wave * 16 + quad * 4 + r;
            if (row < N_NODES) mulv[(size_t)row * 128 + ybase + j] = f2bf(acc[nt][r] + bias);
        }
    }
}

// ---------------- ZDEC (gemm2-pattern): x1cat[:,0:256] = relu(z @ W_dect + b_dec) ----------
__global__ __launch_bounds__(256) void zdec_mfma(const unsigned short* __restrict__ mulv,
                                                 const float* __restrict__ eps,
                                                 const unsigned short* __restrict__ W_dect,
                                                 const float* __restrict__ b_dec,
                                                 unsigned short* __restrict__ x1cat) {
    __shared__ unsigned short Bs[256][72];  // 144B stride -> 2-way banks (free)
    int t = threadIdx.x;
    int wave = t >> 6, lane = t & 63;
    int quad = lane >> 4, m16 = lane & 15;
    int m0 = blockIdx.x * 64;

#pragma unroll
    for (int r = 0; r < 8; ++r) {
        int c = r * 256 + t;
        int row = c >> 3, col = (c & 7) * 8;
        *(ushort8*)&Bs[row][col] = *(const ushort8*)&W_dect[(size_t)row * 64 + col];
    }
    int grow = m0 + wave * 16 + m16;
    if (grow >= N_NODES) grow = N_NODES - 1;

    floatx4 acc[16];
#pragma unroll
    for (int i = 0; i < 16; ++i) acc[i] = (floatx4){0.f, 0.f, 0.f, 0.f};
    __syncthreads();

#pragma unroll
    for (int ks = 0; ks < 2; ++ks) {
        int c0 = ks * 32 + quad * 8;
        ushort8 mu8 = *(const ushort8*)&mulv[(size_t)grow * 128 + c0];
        ushort8 lv8 = *(const ushort8*)&mulv[(size_t)grow * 128 + 64 + c0];
        float4 e0 = *(const float4*)&eps[(size_t)grow * 64 + c0];
        float4 e1 = *(const float4*)&eps[(size_t)grow * 64 + c0 + 4];
        ushort8 zz;
        zz[0] = f2bf(bf2f(mu8[0]) + e0.x * expf(bf2f(lv8[0])));
        zz[1] = f2bf(bf2f(mu8[1]) + e0.y * expf(bf2f(lv8[1])));
        zz[2] = f2bf(bf2f(mu8[2]) + e0.z * expf(bf2f(lv8[2])));
        zz[3] = f2bf(bf2f(mu8[3]) + e0.w * expf(bf2f(lv8[3])));
        zz[4] = f2bf(bf2f(mu8[4]) + e1.x * expf(bf2f(lv8[4])));
        zz[5] = f2bf(bf2f(mu8[5]) + e1.y * expf(bf2f(lv8[5])));
        zz[6] = f2bf(bf2f(mu8[6]) + e1.z * expf(bf2f(lv8[6])));
        zz[7] = f2bf(bf2f(mu8[7]) + e1.w * expf(bf2f(lv8[7])));
        short8 af = *(short8*)&zz;
#pragma unroll
        for (int nt = 0; nt < 16; ++nt) {
            short8 bfr = *(const short8*)&Bs[nt * 16 + m16][ks * 32 + quad * 8];
            acc[nt] = __builtin_amdgcn_mfma_f32_16x16x32_bf16(af, bfr, acc[nt], 0, 0, 0);
        }
    }
#pragma unroll
    for (int nt = 0; nt < 16; ++nt) {
        int col = nt * 16 + m16;
        float bias = b_dec[col];
#pragma unroll
        for (int r = 0; r < 4; ++r) {
            int row = m0 + wave * 16 + quad * 4 + r;
            if (row < N_NODES)
                x1cat[(size_t)row * 512 + col] = f2bf(fmaxf(acc[nt][r] + bias, 0.f));
        }
    }
}

// ---------------- GEMM2 v3: S2b padded to 64 cols (128B rows for wide spmm2 gather) --------
__global__ __launch_bounds__(256) void gemm2_mfma(const unsigned short* __restrict__ Xb,
                                                  const unsigned short* __restrict__ Bt,
                                                  unsigned short* __restrict__ S2b) {
    __shared__ unsigned short Bs[NCLS_PAD][520];
    int t = threadIdx.x;
    int wave = t >> 6, lane = t & 63;
    int quad = lane >> 4, m16 = lane & 15;
    int m0 = blockIdx.x * 64;

#pragma unroll
    for (int r = 0; r < 12; ++r) {
        int cidx = r * 256 + t;
        int row = cidx >> 6, col = (cidx & 63) * 8;
        *(ushort8*)&Bs[row][col] = *(const ushort8*)&Bt[(size_t)row * NFEAT + col];
    }

    int arow = m0 + wave * 16 + m16;
    if (arow >= N_NODES) arow = N_NODES - 1;
    const unsigned short* Abase = Xb + (size_t)arow * NFEAT + quad * 8;

    floatx4 acc[3];
#pragma unroll
    for (int i = 0; i < 3; i++) acc[i] = (floatx4){0.f, 0.f, 0.f, 0.f};
    __syncthreads();

#pragma unroll
    for (int k0 = 0; k0 < NFEAT; k0 += 32) {
        short8 af = *(const short8*)(Abase + k0);
#pragma unroll
        for (int nt = 0; nt < 3; nt++) {
            short8 bfr = *(const short8*)&Bs[nt * 16 + m16][k0 + quad * 8];
            acc[nt] = __builtin_amdgcn_mfma_f32_16x16x32_bf16(af, bfr, acc[nt], 0, 0, 0);
        }
    }
#pragma unroll
    for (int nt = 0; nt < 3; nt++) {
        int col = nt * 16 + m16;  // cols 40..47 are zero via W2bt padding
#pragma unroll
        for (int r = 0; r < 4; r++) {
            int row = m0 + wave * 16 + quad * 4 + r;
            if (row < N_NODES) S2b[(size_t)row * 64 + col] = f2bf(acc[nt][r]);
        }
    }
    // zero pad cols 48..63 so spmm2's wide gather reads zeros
#pragma unroll
    for (int r = 0; r < 4; r++) {
        int row = m0 + wave * 16 + quad * 4 + r;
        if (row < N_NODES) S2b[(size_t)row * 64 + 48 + m16] = 0;
    }
}

// ---------------- SpMM2 v2: 8 edges/wave-step, 16B/lane gather + softmax ----------------
// lane = g*8 + c: edge-group g (8 edges in parallel), 8-col chunk c (16B of the 128B row).
// Reduce over g via shfl_xor(8/16/32); softmax over c via shfl_xor(1/2/4).
__global__ __launch_bounds__(256) void spmm2_softmax_kernel(const int* __restrict__ offsets,
                                                            const int2* __restrict__ edges,
                                                            const unsigned short* __restrict__ S2b,
                                                            const float* __restrict__ b2,
                                                            float* __restrict__ out) {
    int wave = threadIdx.x >> 6;
    int lane = threadIdx.x & 63;
    int g = lane >> 3, c = lane & 7;
    int n = blockIdx.x * 4 + wave;
    int beg = offsets[n], end = offsets[n + 1];
    float acc[8];
#pragma unroll
    for (int j = 0; j < 8; ++j) acc[j] = 0.f;

    int i = beg;
    // main loop: 16 edges per iteration (2 per group), no clamps
    for (; i + 16 <= end; i += 16) {
        int2 e0 = edges[i + g];
        int2 e1 = edges[i + 8 + g];
        ushort8 r0 = *(const ushort8*)&S2b[(size_t)e0.x * 64 + c * 8];
        ushort8 r1 = *(const ushort8*)&S2b[(size_t)e1.x * 64 + c * 8];
        float w0 = __builtin_bit_cast(float, e0.y);
        float w1 = __builtin_bit_cast(float, e1.y);
#pragma unroll
        for (int j = 0; j < 8; ++j) acc[j] += w0 * bf2f(r0[j]) + w1 * bf2f(r1[j]);
    }
    // tail: 8 edges per step, clamped
    for (; i < end; i += 8) {
        int idx = i + g;
        int ic = (idx < end) ? idx : (end - 1);
        int2 e = edges[ic];
        float ww = (idx < end) ? __builtin_bit_cast(float, e.y) : 0.f;
        ushort8 r = *(const ushort8*)&S2b[(size_t)e.x * 64 + c * 8];
#pragma unroll
        for (int j = 0; j < 8; ++j) acc[j] += ww * bf2f(r[j]);
    }
    // reduce over edge-groups (lane bits 3,4,5)
#pragma unroll
    for (int off = 8; off <= 32; off <<= 1) {
#pragma unroll
        for (int j = 0; j < 8; ++j) acc[j] += __shfl_xor(acc[j], off);
    }
    // bias; cols >= NCLASS -> -inf
    float v[8];
#pragma unroll
    for (int j = 0; j < 8; ++j) {
        int col = c * 8 + j;
        v[j] = (col < NCLASS) ? (acc[j] + b2[col]) : -INFINITY;
    }
    // softmax over the 8 c-chunks (lane bits 0,1,2) + local 8
    float m = v[0];
#pragma unroll
    for (int j = 1; j < 8; ++j) m = fmaxf(m, v[j]);
#pragma unroll
    for (int off = 1; off <= 4; off <<= 1) m = fmaxf(m, __shfl_xor(m, off));
    float ssum = 0.f;
    float ex[8];
#pragma unroll
    for (int j = 0; j < 8; ++j) {
        ex[j] = (v[j] > -INFINITY) ? expf(v[j] - m) : 0.f;
        ssum += ex[j];
    }
#pragma unroll
    for (int off = 1; off <= 4; off <<= 1) ssum += __shfl_xor(ssum, off);
    float lse = logf(ssum);
    // write: lane's cols c*8..c*8+7, only cols < NCLASS (g==0 lanes write)
    if (g == 0) {
#pragma unroll
        for (int j = 0; j < 8; ++j) {
            int col = c * 8 + j;
            if (col < NCLASS) out[(size_t)n * NCLASS + col] = v[j] - m - lse;
        }
    }
}

extern "C" void kernel_launch(void* const* d_in, const int* in_sizes, int n_in,
                              void* d_out, int out_size, void* d_ws, size_t ws_size,
                              hipStream_t stream) {
    const float* x     = (const float*)d_in[0];
    const int*   esrc  = (const int*)d_in[1];
    const int*   edst  = (const int*)d_in[2];
    const float* ew    = (const float*)d_in[3];
    const float* eps   = (const float*)d_in[4];
    const float* W1    = (const float*)d_in[5];
    const float* b1    = (const float*)d_in[6];
    const float* W_mu  = (const float*)d_in[7];
    const float* b_mu  = (const float*)d_in[8];
    const float* W_lv  = (const float*)d_in[9];
    const float* b_lv  = (const float*)d_in[10];
    const float* W_dec = (const float*)d_in[11];
    const float* b_dec = (const float*)d_in[12];
    const float* W2    = (const float*)d_in[13];
    const float* b2    = (const float*)d_in[14];
    float* out = (float*)d_out;

    // workspace layout (counts & cursor adjacent -> single memset)
    unsigned short* support1b = (unsigned short*)d_ws;                     // 12.8M u16
    unsigned short* x1cat = support1b + (size_t)N_NODES * NHID;            // 25.6M u16
    unsigned short* S2b = x1cat + (size_t)N_NODES * 2 * NHID;              // 3.2M u16 (64-col pad)
    unsigned short* W1t    = S2b + (size_t)N_NODES * 64;
    unsigned short* W2bt   = W1t + (size_t)NHID * NFEAT;
    unsigned short* W_mulvt = W2bt + (size_t)NCLS_PAD * NFEAT;
    unsigned short* W_dect  = W_mulvt + 128 * 256;
    unsigned short* mulv    = W_dect + 256 * 64;   // 50000*128 u16 = 12.8 MB
    int*   counts   = (int*)(((size_t)(mulv + (size_t)N_NODES * 128) + 3) & ~(size_t)3);
    int*   cursor   = counts + N_NODES;
    int*   offsets  = cursor + N_NODES;     // N+1
    int*   blockSums    = offsets + N_NODES + 1;   // NB_SCAN
    int*   blockOffsets = blockSums + NB_SCAN;     // NB_SCAN
    int2*  edges    = (int2*)(blockOffsets + NB_SCAN);
    edges = (int2*)(((size_t)edges + 7) & ~(size_t)7);
    size_t need = (size_t)((char*)(edges + N_EDGES) - (char*)d_ws);
    if (ws_size < need) return;

    hipMemsetAsync(counts, 0, 2 * N_NODES * sizeof(int), stream);  // counts + cursor
    hist_kernel<<<(N_EDGES + 255) / 256, 256, 0, stream>>>(edst, counts);
    scan_block_sums<<<NB_SCAN, 256, 0, stream>>>(counts, blockSums);
    scan_block_offsets<<<1, 256, 0, stream>>>(blockSums, blockOffsets, offsets);
    scan_final<<<NB_SCAN, 256, 0, stream>>>(counts, blockOffsets, offsets);
    scatter_kernel<<<(N_EDGES + 255) / 256, 256, 0, stream>>>(edst, esrc, ew, offsets, cursor,
                                                              edges);

    wprep_kernel<<<800, 256, 0, stream>>>(W1, W2, W_mu, W_lv, W_dec, W1t, W2bt, W_mulvt, W_dect);
    dim3 g1((N_NODES + 127) / 128, 2);
    gemm1_mfma<<<g1, 256, 0, stream>>>(x, W1t, support1b);
    spmm1_kernel<<<N_NODES / 4, 256, 0, stream>>>(offsets, edges, support1b, b1, x1cat);
    dim3 gm((N_NODES + 63) / 64, 2);
    mulv_mfma<<<gm, 256, 0, stream>>>(x1cat, W_mulvt, b_mu, b_lv, mulv);
    zdec_mfma<<<(N_NODES + 63) / 64, 256, 0, stream>>>(mulv, eps, W_dect, b_dec, x1cat);
    gemm2_mfma<<<(N_NODES + 63) / 64, 256, 0, stream>>>(x1cat, W2bt, S2b);
    spmm2_softmax_kernel<<<N_NODES / 4, 256, 0, stream>>>(offsets, edges, S2b, b2, out);
}

// Round 10
// 438.848 us; speedup vs baseline: 1.0411x; 1.0411x over previous
//
#include <hip/hip_runtime.h>
#include <math.h>

#define N_NODES 50000
#define N_EDGES 800000
#define NFEAT 512
#define NHID 256
#define NCODE 64
#define NCLASS 40
#define NCLS_PAD 48
#define NB_SCAN 196  // ceil(50000/256)

typedef __attribute__((ext_vector_type(8))) short short8;
typedef __attribute__((ext_vector_type(8))) unsigned short ushort8;
typedef __attribute__((ext_vector_type(4))) unsigned short ushort4v;
typedef __attribute__((ext_vector_type(4))) float floatx4;

__device__ inline unsigned short f2bf(float f) {
    unsigned u = __builtin_bit_cast(unsigned, f);
    u += 0x7fff + ((u >> 16) & 1);
    return (unsigned short)(u >> 16);
}
__device__ inline float bf2f(unsigned short h) {
    return __builtin_bit_cast(float, (unsigned)h << 16);
}
// packed fp32->bf16 (RNE), 2 elems/instr
__device__ inline unsigned pkbf(float lo, float hi) {
    unsigned r;
    asm("v_cvt_pk_bf16_f32 %0, %1, %2" : "=v"(r) : "v"(lo), "v"(hi));
    return r;
}
// async global->LDS 16B DMA (dest = wave-uniform base + lane*16)
__device__ inline void gload_lds16(const void* g, void* l) {
    __builtin_amdgcn_global_load_lds(
        (const __attribute__((address_space(1))) unsigned int*)g,
        (__attribute__((address_space(3))) unsigned int*)l, 16, 0, 0);
}

// ---------------- CSR build (by dst) ----------------
__global__ __launch_bounds__(256) void hist_kernel(const int* __restrict__ dst,
                                                   int* __restrict__ counts) {
    int t = blockIdx.x * 256 + threadIdx.x;
    if (t < N_EDGES) atomicAdd(&counts[dst[t]], 1);
}

// 3-phase device scan
__global__ __launch_bounds__(256) void scan_block_sums(const int* __restrict__ counts,
                                                       int* __restrict__ blockSums) {
    __shared__ int red[256];
    int t = threadIdx.x;
    int i = blockIdx.x * 256 + t;
    red[t] = (i < N_NODES) ? counts[i] : 0;
    __syncthreads();
#pragma unroll
    for (int off = 128; off > 0; off >>= 1) {
        if (t < off) red[t] += red[t + off];
        __syncthreads();
    }
    if (t == 0) blockSums[blockIdx.x] = red[0];
}

__global__ __launch_bounds__(256) void scan_block_offsets(const int* __restrict__ blockSums,
                                                          int* __restrict__ blockOffsets,
                                                          int* __restrict__ offsets) {
    __shared__ int s[256];
    int t = threadIdx.x;
    int v = (t < NB_SCAN) ? blockSums[t] : 0;
    s[t] = v;
    __syncthreads();
#pragma unroll
    for (int off = 1; off < 256; off <<= 1) {
        int x = (t >= off) ? s[t - off] : 0;
        __syncthreads();
        s[t] += x;
        __syncthreads();
    }
    if (t < NB_SCAN) blockOffsets[t] = s[t] - v;  // exclusive
    if (t == 255) offsets[N_NODES] = s[255];      // total = E
}

__global__ __launch_bounds__(256) void scan_final(const int* __restrict__ counts,
                                                  const int* __restrict__ blockOffsets,
                                                  int* __restrict__ offsets) {
    __shared__ int s[256];
    int t = threadIdx.x;
    int i = blockIdx.x * 256 + t;
    int v = (i < N_NODES) ? counts[i] : 0;
    s[t] = v;
    __syncthreads();
#pragma unroll
    for (int off = 1; off < 256; off <<= 1) {
        int x = (t >= off) ? s[t - off] : 0;
        __syncthreads();
        s[t] += x;
        __syncthreads();
    }
    if (i < N_NODES) offsets[i] = blockOffsets[blockIdx.x] + s[t] - v;  // exclusive
}

// scatter edges into dst-sorted order as packed (src, w_bits) int2
__global__ __launch_bounds__(256) void scatter_kernel(const int* __restrict__ dst,
                                                      const int* __restrict__ src,
                                                      const float* __restrict__ w,
                                                      const int* __restrict__ offsets,
                                                      int* __restrict__ cursor,
                                                      int2* __restrict__ edges) {
    int t = blockIdx.x * 256 + threadIdx.x;
    if (t < N_EDGES) {
        int d = dst[t];
        int pos = offsets[d] + atomicAdd(&cursor[d], 1);
        edges[pos] = make_int2(src[t], __builtin_bit_cast(int, w[t]));
    }
}

// ---------------- Fused weight prep: W1t / W2bt / W_mulvt / W_dect ----------------
__global__ __launch_bounds__(256) void wprep_kernel(const float* __restrict__ W1,
                                                    const float* __restrict__ W2,
                                                    const float* __restrict__ W_mu,
                                                    const float* __restrict__ W_lv,
                                                    const float* __restrict__ W_dec,
                                                    unsigned short* __restrict__ W1t,
                                                    unsigned short* __restrict__ W2bt,
                                                    unsigned short* __restrict__ W_mulvt,
                                                    unsigned short* __restrict__ W_dect) {
    int idx = blockIdx.x * 256 + threadIdx.x;
    if (idx < NFEAT * NHID) {
        int k = idx >> 8;
        int n = idx & 255;
        W1t[(size_t)n * NFEAT + k] = f2bf(W1[idx]);
    } else if (idx < NFEAT * NHID + NCLS_PAD * NFEAT) {
        int i2 = idx - NFEAT * NHID;
        int n = i2 >> 9;
        int k = i2 & 511;
        W2bt[i2] = (n < NCLASS) ? f2bf(W2[(size_t)k * NCLASS + n]) : (unsigned short)0;
    } else if (idx < NFEAT * NHID + NCLS_PAD * NFEAT + 128 * 256) {
        int i2 = idx - NFEAT * NHID - NCLS_PAD * NFEAT;
        int j = i2 >> 8;
        int k = i2 & 255;
        float v = (j < 64) ? W_mu[(size_t)k * NCODE + j] : W_lv[(size_t)k * NCODE + (j - 64)];
        W_mulvt[i2] = f2bf(v);
    } else if (idx < NFEAT * NHID + NCLS_PAD * NFEAT + 128 * 256 + 256 * 64) {
        int i2 = idx - NFEAT * NHID - NCLS_PAD * NFEAT - 128 * 256;
        int n = i2 >> 6;
        int k = i2 & 63;
        W_dect[i2] = f2bf(W_dec[(size_t)k * NHID + n]);
    }
}

// ---------------- GEMM1 v3: 128x128 tile, BK=64, single-buffer, XOR-swizzled, A reg-prefetch
__global__ __launch_bounds__(256) void gemm1_mfma(const float* __restrict__ A,
                                                  const unsigned short* __restrict__ Bt,
                                                  unsigned short* __restrict__ C) {
    __shared__ unsigned short As[128 * 64];
    __shared__ unsigned short Bs[128 * 64];
    int t = threadIdx.x;
    int wave = t >> 6, lane = t & 63;
    int quad = lane >> 4, m16 = lane & 15;
    int wr = wave >> 1, wc = wave & 1;
    int m0 = blockIdx.x * 128;
    int n0 = blockIdx.y * 128;

    int srow = t >> 3;
    int kcs = (t & 7) ^ (srow & 7);  // swizzled source chunk
    const float* Ap[4];
#pragma unroll
    for (int r = 0; r < 4; ++r) {
        int ga = m0 + r * 32 + srow;
        if (ga >= N_NODES) ga = N_NODES - 1;
        Ap[r] = A + (size_t)ga * NFEAT + kcs * 8;
    }
    const unsigned short* Bbase = Bt + (size_t)(n0 + srow) * NFEAT + kcs * 8;

    floatx4 acc[4][4];
#pragma unroll
    for (int m = 0; m < 4; ++m)
#pragma unroll
        for (int n = 0; n < 4; ++n) acc[m][n] = (floatx4){0.f, 0.f, 0.f, 0.f};

    float4 a0[4], a1[4];
#pragma unroll
    for (int r = 0; r < 4; ++r) {
        a0[r] = *(const float4*)(Ap[r]);
        a1[r] = *(const float4*)(Ap[r] + 4);
    }

#pragma unroll
    for (int k0 = 0; k0 < NFEAT; k0 += 64) {
        uint4 aw[4];
#pragma unroll
        for (int r = 0; r < 4; ++r) {
            aw[r].x = pkbf(a0[r].x, a0[r].y);
            aw[r].y = pkbf(a0[r].z, a0[r].w);
            aw[r].z = pkbf(a1[r].x, a1[r].y);
            aw[r].w = pkbf(a1[r].z, a1[r].w);
        }
        __syncthreads();
#pragma unroll
        for (int r = 0; r < 4; ++r)
            gload_lds16(Bbase + (size_t)r * 32 * NFEAT + k0, &Bs[(r * 256 + wave * 64) * 8]);
#pragma unroll
        for (int r = 0; r < 4; ++r) *(uint4*)&As[(r * 256 + t) * 8] = aw[r];
        __syncthreads();
        if (k0 + 64 < NFEAT) {
#pragma unroll
            for (int r = 0; r < 4; ++r) {
                a0[r] = *(const float4*)(Ap[r] + k0 + 64);
                a1[r] = *(const float4*)(Ap[r] + k0 + 68);
            }
        }
#pragma unroll
        for (int c = 0; c < 2; ++c) {
            int sw = ((c * 4 + quad) ^ (m16 & 7)) * 8;
            short8 af[4], bfr[4];
#pragma unroll
            for (int m = 0; m < 4; ++m)
                af[m] = *(const short8*)&As[(wr * 64 + m * 16 + m16) * 64 + sw];
#pragma unroll
            for (int n = 0; n < 4; ++n)
                bfr[n] = *(const short8*)&Bs[(wc * 64 + n * 16 + m16) * 64 + sw];
#pragma unroll
            for (int m = 0; m < 4; ++m)
#pragma unroll
                for (int n = 0; n < 4; ++n)
                    acc[m][n] =
                        __builtin_amdgcn_mfma_f32_16x16x32_bf16(af[m], bfr[n], acc[m][n], 0, 0, 0);
        }
    }
#pragma unroll
    for (int m = 0; m < 4; ++m) {
#pragma unroll
        for (int n = 0; n < 4; ++n) {
            int col = n0 + wc * 64 + n * 16 + m16;
#pragma unroll
            for (int r = 0; r < 4; ++r) {
                int row = m0 + wr * 64 + m * 16 + quad * 4 + r;
                if (row < N_NODES) C[(size_t)row * NHID + col] = f2bf(acc[m][n][r]);
            }
        }
    }
}

// ---------------- SpMM1 v1 (proven 60us): 8-edge unroll, 8B/lane, max TLP ----------------
__global__ __launch_bounds__(256) void spmm1_kernel(const int* __restrict__ offsets,
                                                    const int2* __restrict__ edges,
                                                    const unsigned short* __restrict__ S1b,
                                                    const float* __restrict__ b1,
                                                    unsigned short* __restrict__ x1cat) {
    int n = blockIdx.x * 4 + (threadIdx.x >> 6);
    int lane = threadIdx.x & 63;
    int beg = offsets[n], end = offsets[n + 1];
    float ax = 0.f, ay = 0.f, az = 0.f, aw = 0.f;
    int i = beg;
    for (; i + 8 <= end; i += 8) {
        int2 e[8];
        ushort4v r[8];
#pragma unroll
        for (int u = 0; u < 8; u++) e[u] = edges[i + u];
#pragma unroll
        for (int u = 0; u < 8; u++)
            r[u] = *(const ushort4v*)&S1b[(size_t)e[u].x * NHID + lane * 4];
#pragma unroll
        for (int u = 0; u < 8; u++) {
            float ww = __builtin_bit_cast(float, e[u].y);
            ax += ww * bf2f(r[u][0]);
            ay += ww * bf2f(r[u][1]);
            az += ww * bf2f(r[u][2]);
            aw += ww * bf2f(r[u][3]);
        }
    }
    for (; i < end; i++) {
        int2 e = edges[i];
        float ww = __builtin_bit_cast(float, e.y);
        ushort4v r = *(const ushort4v*)&S1b[(size_t)e.x * NHID + lane * 4];
        ax += ww * bf2f(r[0]); ay += ww * bf2f(r[1]);
        az += ww * bf2f(r[2]); aw += ww * bf2f(r[3]);
    }
    float4 bb = *(const float4*)&b1[lane * 4];
    ushort4v hb;
    hb[0] = f2bf(fmaxf(ax + bb.x, 0.f));
    hb[1] = f2bf(fmaxf(ay + bb.y, 0.f));
    hb[2] = f2bf(fmaxf(az + bb.z, 0.f));
    hb[3] = f2bf(fmaxf(aw + bb.w, 0.f));
    *(ushort4v*)&x1cat[(size_t)n * (2 * NHID) + NHID + lane * 4] = hb;
}

// ---------------- MULV (gemm2-pattern): mulv[:,y*64..] = h1 @ W_mulvt[y-half] + bias --------
__global__ __launch_bounds__(256) void mulv_mfma(const unsigned short* __restrict__ x1cat,
                                                 const unsigned short* __restrict__ W_mulvt,
                                                 const float* __restrict__ b_mu,
                                                 const float* __restrict__ b_lv,
                                                 unsigned short* __restrict__ mulv) {
    __shared__ unsigned short Bs[64][264];  // 528B stride -> 2-way banks (free)
    int t = threadIdx.x;
    int wave = t >> 6, lane = t & 63;
    int quad = lane >> 4, m16 = lane & 15;
    int m0 = blockIdx.x * 64;
    int ybase = blockIdx.y * 64;

#pragma unroll
    for (int r = 0; r < 8; ++r) {
        int c = r * 256 + t;
        int row = c >> 5, col = (c & 31) * 8;
        *(ushort8*)&Bs[row][col] = *(const ushort8*)&W_mulvt[(size_t)(ybase + row) * 256 + col];
    }
    int arow = m0 + wave * 16 + m16;
    if (arow >= N_NODES) arow = N_NODES - 1;
    const unsigned short* Abase = x1cat + (size_t)arow * 512 + 256 + quad * 8;

    floatx4 acc[4];
#pragma unroll
    for (int i = 0; i < 4; ++i) acc[i] = (floatx4){0.f, 0.f, 0.f, 0.f};
    __syncthreads();

#pragma unroll
    for (int k0 = 0; k0 < 256; k0 += 32) {
        short8 af = *(const short8*)(Abase + k0);
#pragma unroll
        for (int nt = 0; nt < 4; ++nt) {
            short8 bfr = *(const short8*)&Bs[nt * 16 + m16][k0 + quad * 8];
            acc[nt] = __builtin_amdgcn_mfma_f32_16x16x32_bf16(af, bfr, acc[nt], 0, 0, 0);
        }
    }
    const float* bias_v = blockIdx.y ? b_lv : b_mu;
#pragma unroll
    for (int nt = 0; nt < 4; ++nt) {
        int j = nt * 16 + m16;
        float bias = bias_v[j];
#pragma unroll
        for (int r = 0; r < 4; ++r) {
            int row = m0 + wave * 16 + quad * 4 + r;
            if (row < N_NODES) mulv[(size_t)row * 128 + ybase + j] = f2bf(acc[nt][r] + bias);
        }
    }
}

// ---------------- ZDEC (gemm2-pattern): x1cat[:,0:256] = relu(z @ W_dect + b_dec) ----------
__global__ __launch_bounds__(256) void zdec_mfma(const unsigned short* __restrict__ mulv,
                                                 const float* __restrict__ eps,
                                                 const unsigned short* __restrict__ W_dect,
                                                 const float* __restrict__ b_dec,
                                                 unsigned short* __restrict__ x1cat) {
    __shared__ unsigned short Bs[256][72];  // 144B stride -> 2-way banks (free)
    int t = threadIdx.x;
    int wave = t >> 6, lane = t & 63;
    int quad = lane >> 4, m16 = lane & 15;
    int m0 = blockIdx.x * 64;

#pragma unroll
    for (int r = 0; r < 8; ++r) {
        int c = r * 256 + t;
        int row = c >> 3, col = (c & 7) * 8;
        *(ushort8*)&Bs[row][col] = *(const ushort8*)&W_dect[(size_t)row * 64 + col];
    }
    int grow = m0 + wave * 16 + m16;
    if (grow >= N_NODES) grow = N_NODES - 1;

    floatx4 acc[16];
#pragma unroll
    for (int i = 0; i < 16; ++i) acc[i] = (floatx4){0.f, 0.f, 0.f, 0.f};
    __syncthreads();

#pragma unroll
    for (int ks = 0; ks < 2; ++ks) {
        int c0 = ks * 32 + quad * 8;
        ushort8 mu8 = *(const ushort8*)&mulv[(size_t)grow * 128 + c0];
        ushort8 lv8 = *(const ushort8*)&mulv[(size_t)grow * 128 + 64 + c0];
        float4 e0 = *(const float4*)&eps[(size_t)grow * 64 + c0];
        float4 e1 = *(const float4*)&eps[(size_t)grow * 64 + c0 + 4];
        ushort8 zz;
        zz[0] = f2bf(bf2f(mu8[0]) + e0.x * expf(bf2f(lv8[0])));
        zz[1] = f2bf(bf2f(mu8[1]) + e0.y * expf(bf2f(lv8[1])));
        zz[2] = f2bf(bf2f(mu8[2]) + e0.z * expf(bf2f(lv8[2])));
        zz[3] = f2bf(bf2f(mu8[3]) + e0.w * expf(bf2f(lv8[3])));
        zz[4] = f2bf(bf2f(mu8[4]) + e1.x * expf(bf2f(lv8[4])));
        zz[5] = f2bf(bf2f(mu8[5]) + e1.y * expf(bf2f(lv8[5])));
        zz[6] = f2bf(bf2f(mu8[6]) + e1.z * expf(bf2f(lv8[6])));
        zz[7] = f2bf(bf2f(mu8[7]) + e1.w * expf(bf2f(lv8[7])));
        short8 af = *(short8*)&zz;
#pragma unroll
        for (int nt = 0; nt < 16; ++nt) {
            short8 bfr = *(const short8*)&Bs[nt * 16 + m16][ks * 32 + quad * 8];
            acc[nt] = __builtin_amdgcn_mfma_f32_16x16x32_bf16(af, bfr, acc[nt], 0, 0, 0);
        }
    }
#pragma unroll
    for (int nt = 0; nt < 16; ++nt) {
        int col = nt * 16 + m16;
        float bias = b_dec[col];
#pragma unroll
        for (int r = 0; r < 4; ++r) {
            int row = m0 + wave * 16 + quad * 4 + r;
            if (row < N_NODES)
                x1cat[(size_t)row * 512 + col] = f2bf(fmaxf(acc[nt][r] + bias, 0.f));
        }
    }
}

// ---------------- GEMM2 v3: S2b padded to 64 cols (128B rows for wide spmm2 gather) --------
__global__ __launch_bounds__(256) void gemm2_mfma(const unsigned short* __restrict__ Xb,
                                                  const unsigned short* __restrict__ Bt,
                                                  unsigned short* __restrict__ S2b) {
    __shared__ unsigned short Bs[NCLS_PAD][520];
    int t = threadIdx.x;
    int wave = t >> 6, lane = t & 63;
    int quad = lane >> 4, m16 = lane & 15;
    int m0 = blockIdx.x * 64;

#pragma unroll
    for (int r = 0; r < 12; ++r) {
        int cidx = r * 256 + t;
        int row = cidx >> 6, col = (cidx & 63) * 8;
        *(ushort8*)&Bs[row][col] = *(const ushort8*)&Bt[(size_t)row * NFEAT + col];
    }

    int arow = m0 + wave * 16 + m16;
    if (arow >= N_NODES) arow = N_NODES - 1;
    const unsigned short* Abase = Xb + (size_t)arow * NFEAT + quad * 8;

    floatx4 acc[3];
#pragma unroll
    for (int i = 0; i < 3; i++) acc[i] = (floatx4){0.f, 0.f, 0.f, 0.f};
    __syncthreads();

#pragma unroll
    for (int k0 = 0; k0 < NFEAT; k0 += 32) {
        short8 af = *(const short8*)(Abase + k0);
#pragma unroll
        for (int nt = 0; nt < 3; nt++) {
            short8 bfr = *(const short8*)&Bs[nt * 16 + m16][k0 + quad * 8];
            acc[nt] = __builtin_amdgcn_mfma_f32_16x16x32_bf16(af, bfr, acc[nt], 0, 0, 0);
        }
    }
#pragma unroll
    for (int nt = 0; nt < 3; nt++) {
        int col = nt * 16 + m16;  // cols 40..47 are zero via W2bt padding
#pragma unroll
        for (int r = 0; r < 4; r++) {
            int row = m0 + wave * 16 + quad * 4 + r;
            if (row < N_NODES) S2b[(size_t)row * 64 + col] = f2bf(acc[nt][r]);
        }
    }
    // zero pad cols 48..63 so spmm2's wide gather reads zeros
#pragma unroll
    for (int r = 0; r < 4; r++) {
        int row = m0 + wave * 16 + quad * 4 + r;
        if (row < N_NODES) S2b[(size_t)row * 64 + 48 + m16] = 0;
    }
}

// ---------------- SpMM2 v2: 8 edges/wave-step, 16B/lane gather + softmax ----------------
__global__ __launch_bounds__(256) void spmm2_softmax_kernel(const int* __restrict__ offsets,
                                                            const int2* __restrict__ edges,
                                                            const unsigned short* __restrict__ S2b,
                                                            const float* __restrict__ b2,
                                                            float* __restrict__ out) {
    int wave = threadIdx.x >> 6;
    int lane = threadIdx.x & 63;
    int g = lane >> 3, c = lane & 7;
    int n = blockIdx.x * 4 + wave;
    int beg = offsets[n], end = offsets[n + 1];
    float acc[8];
#pragma unroll
    for (int j = 0; j < 8; ++j) acc[j] = 0.f;

    int i = beg;
    // main loop: 16 edges per iteration (2 per group), no clamps
    for (; i + 16 <= end; i += 16) {
        int2 e0 = edges[i + g];
        int2 e1 = edges[i + 8 + g];
        ushort8 r0 = *(const ushort8*)&S2b[(size_t)e0.x * 64 + c * 8];
        ushort8 r1 = *(const ushort8*)&S2b[(size_t)e1.x * 64 + c * 8];
        float w0 = __builtin_bit_cast(float, e0.y);
        float w1 = __builtin_bit_cast(float, e1.y);
#pragma unroll
        for (int j = 0; j < 8; ++j) acc[j] += w0 * bf2f(r0[j]) + w1 * bf2f(r1[j]);
    }
    // tail: 8 edges per step, clamped
    for (; i < end; i += 8) {
        int idx = i + g;
        int ic = (idx < end) ? idx : (end - 1);
        int2 e = edges[ic];
        float ww = (idx < end) ? __builtin_bit_cast(float, e.y) : 0.f;
        ushort8 r = *(const ushort8*)&S2b[(size_t)e.x * 64 + c * 8];
#pragma unroll
        for (int j = 0; j < 8; ++j) acc[j] += ww * bf2f(r[j]);
    }
    // reduce over edge-groups (lane bits 3,4,5)
#pragma unroll
    for (int off = 8; off <= 32; off <<= 1) {
#pragma unroll
        for (int j = 0; j < 8; ++j) acc[j] += __shfl_xor(acc[j], off);
    }
    // bias; cols >= NCLASS -> -inf
    float v[8];
#pragma unroll
    for (int j = 0; j < 8; ++j) {
        int col = c * 8 + j;
        v[j] = (col < NCLASS) ? (acc[j] + b2[col]) : -INFINITY;
    }
    // softmax over the 8 c-chunks (lane bits 0,1,2) + local 8
    float m = v[0];
#pragma unroll
    for (int j = 1; j < 8; ++j) m = fmaxf(m, v[j]);
#pragma unroll
    for (int off = 1; off <= 4; off <<= 1) m = fmaxf(m, __shfl_xor(m, off));
    float ssum = 0.f;
    float ex[8];
#pragma unroll
    for (int j = 0; j < 8; ++j) {
        ex[j] = (v[j] > -INFINITY) ? expf(v[j] - m) : 0.f;
        ssum += ex[j];
    }
#pragma unroll
    for (int off = 1; off <= 4; off <<= 1) ssum += __shfl_xor(ssum, off);
    float lse = logf(ssum);
    // write: lane's cols c*8..c*8+7, only cols < NCLASS (g==0 lanes write)
    if (g == 0) {
#pragma unroll
        for (int j = 0; j < 8; ++j) {
            int col = c * 8 + j;
            if (col < NCLASS) out[(size_t)n * NCLASS + col] = v[j] - m - lse;
        }
    }
}

extern "C" void kernel_launch(void* const* d_in, const int* in_sizes, int n_in,
                              void* d_out, int out_size, void* d_ws, size_t ws_size,
                              hipStream_t stream) {
    const float* x     = (const float*)d_in[0];
    const int*   esrc  = (const int*)d_in[1];
    const int*   edst  = (const int*)d_in[2];
    const float* ew    = (const float*)d_in[3];
    const float* eps   = (const float*)d_in[4];
    const float* W1    = (const float*)d_in[5];
    const float* b1    = (const float*)d_in[6];
    const float* W_mu  = (const float*)d_in[7];
    const float* b_mu  = (const float*)d_in[8];
    const float* W_lv  = (const float*)d_in[9];
    const float* b_lv  = (const float*)d_in[10];
    const float* W_dec = (const float*)d_in[11];
    const float* b_dec = (const float*)d_in[12];
    const float* W2    = (const float*)d_in[13];
    const float* b2    = (const float*)d_in[14];
    float* out = (float*)d_out;

    // workspace layout (counts & cursor adjacent -> single memset)
    unsigned short* support1b = (unsigned short*)d_ws;                     // 12.8M u16
    unsigned short* x1cat = support1b + (size_t)N_NODES * NHID;            // 25.6M u16
    unsigned short* S2b = x1cat + (size_t)N_NODES * 2 * NHID;              // 3.2M u16 (64-col pad)
    unsigned short* W1t    = S2b + (size_t)N_NODES * 64;
    unsigned short* W2bt   = W1t + (size_t)NHID * NFEAT;
    unsigned short* W_mulvt = W2bt + (size_t)NCLS_PAD * NFEAT;
    unsigned short* W_dect  = W_mulvt + 128 * 256;
    unsigned short* mulv    = W_dect + 256 * 64;   // 50000*128 u16 = 12.8 MB
    int*   counts   = (int*)(((size_t)(mulv + (size_t)N_NODES * 128) + 3) & ~(size_t)3);
    int*   cursor   = counts + N_NODES;
    int*   offsets  = cursor + N_NODES;     // N+1
    int*   blockSums    = offsets + N_NODES + 1;   // NB_SCAN
    int*   blockOffsets = blockSums + NB_SCAN;     // NB_SCAN
    int2*  edges    = (int2*)(blockOffsets + NB_SCAN);
    edges = (int2*)(((size_t)edges + 7) & ~(size_t)7);
    size_t need = (size_t)((char*)(edges + N_EDGES) - (char*)d_ws);
    if (ws_size < need) return;

    hipMemsetAsync(counts, 0, 2 * N_NODES * sizeof(int), stream);  // counts + cursor
    hist_kernel<<<(N_EDGES + 255) / 256, 256, 0, stream>>>(edst, counts);
    scan_block_sums<<<NB_SCAN, 256, 0, stream>>>(counts, blockSums);
    scan_block_offsets<<<1, 256, 0, stream>>>(blockSums, blockOffsets, offsets);
    scan_final<<<NB_SCAN, 256, 0, stream>>>(counts, blockOffsets, offsets);
    scatter_kernel<<<(N_EDGES + 255) / 256, 256, 0, stream>>>(edst, esrc, ew, offsets, cursor,
                                                              edges);

    wprep_kernel<<<800, 256, 0, stream>>>(W1, W2, W_mu, W_lv, W_dec, W1t, W2bt, W_mulvt, W_dect);
    dim3 g1((N_NODES + 127) / 128, 2);
    gemm1_mfma<<<g1, 256, 0, stream>>>(x, W1t, support1b);
    spmm1_kernel<<<N_NODES / 4, 256, 0, stream>>>(offsets, edges, support1b, b1, x1cat);
    dim3 gm((N_NODES + 63) / 64, 2);
    mulv_mfma<<<gm, 256, 0, stream>>>(x1cat, W_mulvt, b_mu, b_lv, mulv);
    zdec_mfma<<<(N_NODES + 63) / 64, 256, 0, stream>>>(mulv, eps, W_dect, b_dec, x1cat);
    gemm2_mfma<<<(N_NODES + 63) / 64, 256, 0, stream>>>(x1cat, W2bt, S2b);
    spmm2_softmax_kernel<<<N_NODES / 4, 256, 0, stream>>>(offsets, edges, S2b, b2, out);
}

// Round 11
// 437.431 us; speedup vs baseline: 1.0445x; 1.0032x over previous
//
#include <hip/hip_runtime.h>
#include <math.h>

#define N_NODES 50000
#define N_EDGES 800000
#define NFEAT 512
#define NHID 256
#define NCODE 64
#define NCLASS 40
#define NCLS_PAD 48
#define NB_SCAN 196  // ceil(50000/256)

typedef __attribute__((ext_vector_type(8))) short short8;
typedef __attribute__((ext_vector_type(8))) unsigned short ushort8;
typedef __attribute__((ext_vector_type(4))) unsigned short ushort4v;
typedef __attribute__((ext_vector_type(4))) float floatx4;

__device__ inline unsigned short f2bf(float f) {
    unsigned u = __builtin_bit_cast(unsigned, f);
    u += 0x7fff + ((u >> 16) & 1);
    return (unsigned short)(u >> 16);
}
__device__ inline float bf2f(unsigned short h) {
    return __builtin_bit_cast(float, (unsigned)h << 16);
}
// packed fp32->bf16 (RNE), 2 elems/instr
__device__ inline unsigned pkbf(float lo, float hi) {
    unsigned r;
    asm("v_cvt_pk_bf16_f32 %0, %1, %2" : "=v"(r) : "v"(lo), "v"(hi));
    return r;
}
// async global->LDS 16B DMA (dest = wave-uniform base + lane*16)
__device__ inline void gload_lds16(const void* g, void* l) {
    __builtin_amdgcn_global_load_lds(
        (const __attribute__((address_space(1))) unsigned int*)g,
        (__attribute__((address_space(3))) unsigned int*)l, 16, 0, 0);
}

// ---------------- CSR build (by dst) ----------------
__global__ __launch_bounds__(256) void hist_kernel(const int* __restrict__ dst,
                                                   int* __restrict__ counts) {
    int t = blockIdx.x * 256 + threadIdx.x;
    if (t < N_EDGES) atomicAdd(&counts[dst[t]], 1);
}

// 3-phase device scan
__global__ __launch_bounds__(256) void scan_block_sums(const int* __restrict__ counts,
                                                       int* __restrict__ blockSums) {
    __shared__ int red[256];
    int t = threadIdx.x;
    int i = blockIdx.x * 256 + t;
    red[t] = (i < N_NODES) ? counts[i] : 0;
    __syncthreads();
#pragma unroll
    for (int off = 128; off > 0; off >>= 1) {
        if (t < off) red[t] += red[t + off];
        __syncthreads();
    }
    if (t == 0) blockSums[blockIdx.x] = red[0];
}

__global__ __launch_bounds__(256) void scan_block_offsets(const int* __restrict__ blockSums,
                                                          int* __restrict__ blockOffsets,
                                                          int* __restrict__ offsets) {
    __shared__ int s[256];
    int t = threadIdx.x;
    int v = (t < NB_SCAN) ? blockSums[t] : 0;
    s[t] = v;
    __syncthreads();
#pragma unroll
    for (int off = 1; off < 256; off <<= 1) {
        int x = (t >= off) ? s[t - off] : 0;
        __syncthreads();
        s[t] += x;
        __syncthreads();
    }
    if (t < NB_SCAN) blockOffsets[t] = s[t] - v;  // exclusive
    if (t == 255) offsets[N_NODES] = s[255];      // total = E
}

__global__ __launch_bounds__(256) void scan_final(const int* __restrict__ counts,
                                                  const int* __restrict__ blockOffsets,
                                                  int* __restrict__ offsets) {
    __shared__ int s[256];
    int t = threadIdx.x;
    int i = blockIdx.x * 256 + t;
    int v = (i < N_NODES) ? counts[i] : 0;
    s[t] = v;
    __syncthreads();
#pragma unroll
    for (int off = 1; off < 256; off <<= 1) {
        int x = (t >= off) ? s[t - off] : 0;
        __syncthreads();
        s[t] += x;
        __syncthreads();
    }
    if (i < N_NODES) offsets[i] = blockOffsets[blockIdx.x] + s[t] - v;  // exclusive
}

// scatter edges into dst-sorted order as packed (src, w_bits) int2
__global__ __launch_bounds__(256) void scatter_kernel(const int* __restrict__ dst,
                                                      const int* __restrict__ src,
                                                      const float* __restrict__ w,
                                                      const int* __restrict__ offsets,
                                                      int* __restrict__ cursor,
                                                      int2* __restrict__ edges) {
    int t = blockIdx.x * 256 + threadIdx.x;
    if (t < N_EDGES) {
        int d = dst[t];
        int pos = offsets[d] + atomicAdd(&cursor[d], 1);
        edges[pos] = make_int2(src[t], __builtin_bit_cast(int, w[t]));
    }
}

// ---------------- Fused weight prep: W1t / W2bt / W_mulvt / W_dect ----------------
__global__ __launch_bounds__(256) void wprep_kernel(const float* __restrict__ W1,
                                                    const float* __restrict__ W2,
                                                    const float* __restrict__ W_mu,
                                                    const float* __restrict__ W_lv,
                                                    const float* __restrict__ W_dec,
                                                    unsigned short* __restrict__ W1t,
                                                    unsigned short* __restrict__ W2bt,
                                                    unsigned short* __restrict__ W_mulvt,
                                                    unsigned short* __restrict__ W_dect) {
    int idx = blockIdx.x * 256 + threadIdx.x;
    if (idx < NFEAT * NHID) {
        int k = idx >> 8;
        int n = idx & 255;
        W1t[(size_t)n * NFEAT + k] = f2bf(W1[idx]);
    } else if (idx < NFEAT * NHID + NCLS_PAD * NFEAT) {
        int i2 = idx - NFEAT * NHID;
        int n = i2 >> 9;
        int k = i2 & 511;
        W2bt[i2] = (n < NCLASS) ? f2bf(W2[(size_t)k * NCLASS + n]) : (unsigned short)0;
    } else if (idx < NFEAT * NHID + NCLS_PAD * NFEAT + 128 * 256) {
        int i2 = idx - NFEAT * NHID - NCLS_PAD * NFEAT;
        int j = i2 >> 8;
        int k = i2 & 255;
        float v = (j < 64) ? W_mu[(size_t)k * NCODE + j] : W_lv[(size_t)k * NCODE + (j - 64)];
        W_mulvt[i2] = f2bf(v);
    } else if (idx < NFEAT * NHID + NCLS_PAD * NFEAT + 128 * 256 + 256 * 64) {
        int i2 = idx - NFEAT * NHID - NCLS_PAD * NFEAT - 128 * 256;
        int n = i2 >> 6;
        int k = i2 & 63;
        W_dect[i2] = f2bf(W_dec[(size_t)k * NHID + n]);
    }
}

// ---------------- GEMM1 v3: 128x128 tile, BK=64, single-buffer, XOR-swizzled, A reg-prefetch
__global__ __launch_bounds__(256) void gemm1_mfma(const float* __restrict__ A,
                                                  const unsigned short* __restrict__ Bt,
                                                  unsigned short* __restrict__ C) {
    __shared__ unsigned short As[128 * 64];
    __shared__ unsigned short Bs[128 * 64];
    int t = threadIdx.x;
    int wave = t >> 6, lane = t & 63;
    int quad = lane >> 4, m16 = lane & 15;
    int wr = wave >> 1, wc = wave & 1;
    int m0 = blockIdx.x * 128;
    int n0 = blockIdx.y * 128;

    int srow = t >> 3;
    int kcs = (t & 7) ^ (srow & 7);  // swizzled source chunk
    const float* Ap[4];
#pragma unroll
    for (int r = 0; r < 4; ++r) {
        int ga = m0 + r * 32 + srow;
        if (ga >= N_NODES) ga = N_NODES - 1;
        Ap[r] = A + (size_t)ga * NFEAT + kcs * 8;
    }
    const unsigned short* Bbase = Bt + (size_t)(n0 + srow) * NFEAT + kcs * 8;

    floatx4 acc[4][4];
#pragma unroll
    for (int m = 0; m < 4; ++m)
#pragma unroll
        for (int n = 0; n < 4; ++n) acc[m][n] = (floatx4){0.f, 0.f, 0.f, 0.f};

    float4 a0[4], a1[4];
#pragma unroll
    for (int r = 0; r < 4; ++r) {
        a0[r] = *(const float4*)(Ap[r]);
        a1[r] = *(const float4*)(Ap[r] + 4);
    }

#pragma unroll
    for (int k0 = 0; k0 < NFEAT; k0 += 64) {
        uint4 aw[4];
#pragma unroll
        for (int r = 0; r < 4; ++r) {
            aw[r].x = pkbf(a0[r].x, a0[r].y);
            aw[r].y = pkbf(a0[r].z, a0[r].w);
            aw[r].z = pkbf(a1[r].x, a1[r].y);
            aw[r].w = pkbf(a1[r].z, a1[r].w);
        }
        __syncthreads();
#pragma unroll
        for (int r = 0; r < 4; ++r)
            gload_lds16(Bbase + (size_t)r * 32 * NFEAT + k0, &Bs[(r * 256 + wave * 64) * 8]);
#pragma unroll
        for (int r = 0; r < 4; ++r) *(uint4*)&As[(r * 256 + t) * 8] = aw[r];
        __syncthreads();
        if (k0 + 64 < NFEAT) {
#pragma unroll
            for (int r = 0; r < 4; ++r) {
                a0[r] = *(const float4*)(Ap[r] + k0 + 64);
                a1[r] = *(const float4*)(Ap[r] + k0 + 68);
            }
        }
#pragma unroll
        for (int c = 0; c < 2; ++c) {
            int sw = ((c * 4 + quad) ^ (m16 & 7)) * 8;
            short8 af[4], bfr[4];
#pragma unroll
            for (int m = 0; m < 4; ++m)
                af[m] = *(const short8*)&As[(wr * 64 + m * 16 + m16) * 64 + sw];
#pragma unroll
            for (int n = 0; n < 4; ++n)
                bfr[n] = *(const short8*)&Bs[(wc * 64 + n * 16 + m16) * 64 + sw];
#pragma unroll
            for (int m = 0; m < 4; ++m)
#pragma unroll
                for (int n = 0; n < 4; ++n)
                    acc[m][n] =
                        __builtin_amdgcn_mfma_f32_16x16x32_bf16(af[m], bfr[n], acc[m][n], 0, 0, 0);
        }
    }
#pragma unroll
    for (int m = 0; m < 4; ++m) {
#pragma unroll
        for (int n = 0; n < 4; ++n) {
            int col = n0 + wc * 64 + n * 16 + m16;
#pragma unroll
            for (int r = 0; r < 4; ++r) {
                int row = m0 + wr * 64 + m * 16 + quad * 4 + r;
                if (row < N_NODES) C[(size_t)row * NHID + col] = f2bf(acc[m][n][r]);
            }
        }
    }
}

// ---------------- SpMM1 v1 (proven 60us): 8-edge unroll, 8B/lane, max TLP ----------------
__global__ __launch_bounds__(256) void spmm1_kernel(const int* __restrict__ offsets,
                                                    const int2* __restrict__ edges,
                                                    const unsigned short* __restrict__ S1b,
                                                    const float* __restrict__ b1,
                                                    unsigned short* __restrict__ x1cat) {
    int n = blockIdx.x * 4 + (threadIdx.x >> 6);
    int lane = threadIdx.x & 63;
    int beg = offsets[n], end = offsets[n + 1];
    float ax = 0.f, ay = 0.f, az = 0.f, aw = 0.f;
    int i = beg;
    for (; i + 8 <= end; i += 8) {
        int2 e[8];
        ushort4v r[8];
#pragma unroll
        for (int u = 0; u < 8; u++) e[u] = edges[i + u];
#pragma unroll
        for (int u = 0; u < 8; u++)
            r[u] = *(const ushort4v*)&S1b[(size_t)e[u].x * NHID + lane * 4];
#pragma unroll
        for (int u = 0; u < 8; u++) {
            float ww = __builtin_bit_cast(float, e[u].y);
            ax += ww * bf2f(r[u][0]);
            ay += ww * bf2f(r[u][1]);
            az += ww * bf2f(r[u][2]);
            aw += ww * bf2f(r[u][3]);
        }
    }
    for (; i < end; i++) {
        int2 e = edges[i];
        float ww = __builtin_bit_cast(float, e.y);
        ushort4v r = *(const ushort4v*)&S1b[(size_t)e.x * NHID + lane * 4];
        ax += ww * bf2f(r[0]); ay += ww * bf2f(r[1]);
        az += ww * bf2f(r[2]); aw += ww * bf2f(r[3]);
    }
    float4 bb = *(const float4*)&b1[lane * 4];
    ushort4v hb;
    hb[0] = f2bf(fmaxf(ax + bb.x, 0.f));
    hb[1] = f2bf(fmaxf(ay + bb.y, 0.f));
    hb[2] = f2bf(fmaxf(az + bb.z, 0.f));
    hb[3] = f2bf(fmaxf(aw + bb.w, 0.f));
    *(ushort4v*)&x1cat[(size_t)n * (2 * NHID) + NHID + lane * 4] = hb;
}

// ---------------- FUSED MLP: mulv + zdec in one kernel, 64 rows/block ----------------
// Phase M1: stage Wmu slab (33.8KB LDS) -> amu[4] (fp32 regs). h1 A-frags loaded ONCE to regs.
// Phase M2: restage Wlv slab -> alv[4].
// Phase Z : z = (amu+bmu) + eps*exp(alv+blv) in fp32 regs -> z_bf LDS (9KB).
// Phase D : stage W_dect (36.9KB at offset 9KB) -> x1 = relu(z @ W_dect + b_dec) -> x1cat[:,0:256].
// No mulv global round-trip (saves 25.6MB HBM + 1 dispatch). LDS max 46080B -> 3 blocks/CU.
__global__ __launch_bounds__(256) void mlp_fused(const unsigned short* __restrict__ x1cat_ro,
                                                 const float* __restrict__ eps,
                                                 const float* __restrict__ b_mu,
                                                 const float* __restrict__ b_lv,
                                                 const unsigned short* __restrict__ W_mulvt,
                                                 const float* __restrict__ b_dec,
                                                 const unsigned short* __restrict__ W_dect,
                                                 unsigned short* __restrict__ x1cat) {
    __shared__ unsigned short buf[23040];  // max(64*264, 4*16*72 + 256*72) u16 = 46080B
    int t = threadIdx.x;
    int wave = t >> 6, lane = t & 63;
    int quad = lane >> 4, m16 = lane & 15;
    int m0 = blockIdx.x * 64;

    int arow = m0 + wave * 16 + m16;
    if (arow >= N_NODES) arow = N_NODES - 1;
    // h1 A-fragments: loaded once, reused in both mulv K-loops
    short8 hfr[8];
#pragma unroll
    for (int k = 0; k < 8; ++k)
        hfr[k] = *(const short8*)(x1cat_ro + (size_t)arow * 512 + 256 + k * 32 + quad * 8);

    // ---- phase M1: amu = h1 @ Wmu-slab ----
#pragma unroll
    for (int r = 0; r < 8; ++r) {
        int c = r * 256 + t;
        int row = c >> 5, col = (c & 31) * 8;
        *(ushort8*)&buf[row * 264 + col] = *(const ushort8*)&W_mulvt[(size_t)row * 256 + col];
    }
    floatx4 amu[4], alv[4];
#pragma unroll
    for (int i = 0; i < 4; ++i) amu[i] = (floatx4){0.f, 0.f, 0.f, 0.f};
    __syncthreads();
#pragma unroll
    for (int k = 0; k < 8; ++k) {
#pragma unroll
        for (int nt = 0; nt < 4; ++nt) {
            short8 bfr = *(const short8*)&buf[(nt * 16 + m16) * 264 + k * 32 + quad * 8];
            amu[nt] = __builtin_amdgcn_mfma_f32_16x16x32_bf16(hfr[k], bfr, amu[nt], 0, 0, 0);
        }
    }
    __syncthreads();
    // ---- phase M2: alv = h1 @ Wlv-slab ----
#pragma unroll
    for (int r = 0; r < 8; ++r) {
        int c = r * 256 + t;
        int row = c >> 5, col = (c & 31) * 8;
        *(ushort8*)&buf[row * 264 + col] =
            *(const ushort8*)&W_mulvt[(size_t)(64 + row) * 256 + col];
    }
#pragma unroll
    for (int i = 0; i < 4; ++i) alv[i] = (floatx4){0.f, 0.f, 0.f, 0.f};
    __syncthreads();
#pragma unroll
    for (int k = 0; k < 8; ++k) {
#pragma unroll
        for (int nt = 0; nt < 4; ++nt) {
            short8 bfr = *(const short8*)&buf[(nt * 16 + m16) * 264 + k * 32 + quad * 8];
            alv[nt] = __builtin_amdgcn_mfma_f32_16x16x32_bf16(hfr[k], bfr, alv[nt], 0, 0, 0);
        }
    }
    __syncthreads();  // slab dead; buf free for z_bf + W_dect
    // ---- phase Z: z = (amu+bmu) + eps*exp(alv+blv) -> z_bf LDS (wave-local region) ----
#pragma unroll
    for (int q = 0; q < 4; ++q) {
        int col = q * 16 + m16;
        float bmu = b_mu[col], blv = b_lv[col];
#pragma unroll
        for (int r = 0; r < 4; ++r) {
            int row = m0 + wave * 16 + quad * 4 + r;
            int er = (row < N_NODES) ? row : N_NODES - 1;
            float z = (amu[q][r] + bmu) + eps[(size_t)er * NCODE + col] * expf(alv[q][r] + blv);
            buf[(wave * 16 + quad * 4 + r) * 72 + col] = f2bf(z);
        }
    }
    // stage W_dect at offset 4608 u16 (no overlap with z region)
#pragma unroll
    for (int r = 0; r < 8; ++r) {
        int c = r * 256 + t;
        int row = c >> 3, col = (c & 7) * 8;
        *(ushort8*)&buf[4608 + row * 72 + col] = *(const ushort8*)&W_dect[(size_t)row * 64 + col];
    }
    __syncthreads();
    // ---- phase D: x1 = relu(z @ W_dect + b_dec) ----
    floatx4 acc[16];
#pragma unroll
    for (int i = 0; i < 16; ++i) acc[i] = (floatx4){0.f, 0.f, 0.f, 0.f};
#pragma unroll
    for (int ks = 0; ks < 2; ++ks) {
        short8 af = *(const short8*)&buf[(wave * 16 + m16) * 72 + ks * 32 + quad * 8];
#pragma unroll
        for (int nt = 0; nt < 16; ++nt) {
            short8 bfr = *(const short8*)&buf[4608 + (nt * 16 + m16) * 72 + ks * 32 + quad * 8];
            acc[nt] = __builtin_amdgcn_mfma_f32_16x16x32_bf16(af, bfr, acc[nt], 0, 0, 0);
        }
    }
#pragma unroll
    for (int nt = 0; nt < 16; ++nt) {
        int col = nt * 16 + m16;
        float bias = b_dec[col];
#pragma unroll
        for (int r = 0; r < 4; ++r) {
            int row = m0 + wave * 16 + quad * 4 + r;
            if (row < N_NODES)
                x1cat[(size_t)row * 512 + col] = f2bf(fmaxf(acc[nt][r] + bias, 0.f));
        }
    }
}

// ---------------- GEMM2 v3: S2b padded to 64 cols (128B rows for wide spmm2 gather) --------
__global__ __launch_bounds__(256) void gemm2_mfma(const unsigned short* __restrict__ Xb,
                                                  const unsigned short* __restrict__ Bt,
                                                  unsigned short* __restrict__ S2b) {
    __shared__ unsigned short Bs[NCLS_PAD][520];
    int t = threadIdx.x;
    int wave = t >> 6, lane = t & 63;
    int quad = lane >> 4, m16 = lane & 15;
    int m0 = blockIdx.x * 64;

#pragma unroll
    for (int r = 0; r < 12; ++r) {
        int cidx = r * 256 + t;
        int row = cidx >> 6, col = (cidx & 63) * 8;
        *(ushort8*)&Bs[row][col] = *(const ushort8*)&Bt[(size_t)row * NFEAT + col];
    }

    int arow = m0 + wave * 16 + m16;
    if (arow >= N_NODES) arow = N_NODES - 1;
    const unsigned short* Abase = Xb + (size_t)arow * NFEAT + quad * 8;

    floatx4 acc[3];
#pragma unroll
    for (int i = 0; i < 3; i++) acc[i] = (floatx4){0.f, 0.f, 0.f, 0.f};
    __syncthreads();

#pragma unroll
    for (int k0 = 0; k0 < NFEAT; k0 += 32) {
        short8 af = *(const short8*)(Abase + k0);
#pragma unroll
        for (int nt = 0; nt < 3; nt++) {
            short8 bfr = *(const short8*)&Bs[nt * 16 + m16][k0 + quad * 8];
            acc[nt] = __builtin_amdgcn_mfma_f32_16x16x32_bf16(af, bfr, acc[nt], 0, 0, 0);
        }
    }
#pragma unroll
    for (int nt = 0; nt < 3; nt++) {
        int col = nt * 16 + m16;  // cols 40..47 are zero via W2bt padding
#pragma unroll
        for (int r = 0; r < 4; r++) {
            int row = m0 + wave * 16 + quad * 4 + r;
            if (row < N_NODES) S2b[(size_t)row * 64 + col] = f2bf(acc[nt][r]);
        }
    }
    // zero pad cols 48..63 so spmm2's wide gather reads zeros
#pragma unroll
    for (int r = 0; r < 4; r++) {
        int row = m0 + wave * 16 + quad * 4 + r;
        if (row < N_NODES) S2b[(size_t)row * 64 + 48 + m16] = 0;
    }
}

// ---------------- SpMM2 v2: 8 edges/wave-step, 16B/lane gather + softmax ----------------
__global__ __launch_bounds__(256) void spmm2_softmax_kernel(const int* __restrict__ offsets,
                                                            const int2* __restrict__ edges,
                                                            const unsigned short* __restrict__ S2b,
                                                            const float* __restrict__ b2,
                                                            float* __restrict__ out) {
    int wave = threadIdx.x >> 6;
    int lane = threadIdx.x & 63;
    int g = lane >> 3, c = lane & 7;
    int n = blockIdx.x * 4 + wave;
    int beg = offsets[n], end = offsets[n + 1];
    float acc[8];
#pragma unroll
    for (int j = 0; j < 8; ++j) acc[j] = 0.f;

    int i = beg;
    // main loop: 16 edges per iteration (2 per group), no clamps
    for (; i + 16 <= end; i += 16) {
        int2 e0 = edges[i + g];
        int2 e1 = edges[i + 8 + g];
        ushort8 r0 = *(const ushort8*)&S2b[(size_t)e0.x * 64 + c * 8];
        ushort8 r1 = *(const ushort8*)&S2b[(size_t)e1.x * 64 + c * 8];
        float w0 = __builtin_bit_cast(float, e0.y);
        float w1 = __builtin_bit_cast(float, e1.y);
#pragma unroll
        for (int j = 0; j < 8; ++j) acc[j] += w0 * bf2f(r0[j]) + w1 * bf2f(r1[j]);
    }
    // tail: 8 edges per step, clamped
    for (; i < end; i += 8) {
        int idx = i + g;
        int ic = (idx < end) ? idx : (end - 1);
        int2 e = edges[ic];
        float ww = (idx < end) ? __builtin_bit_cast(float, e.y) : 0.f;
        ushort8 r = *(const ushort8*)&S2b[(size_t)e.x * 64 + c * 8];
#pragma unroll
        for (int j = 0; j < 8; ++j) acc[j] += ww * bf2f(r[j]);
    }
    // reduce over edge-groups (lane bits 3,4,5)
#pragma unroll
    for (int off = 8; off <= 32; off <<= 1) {
#pragma unroll
        for (int j = 0; j < 8; ++j) acc[j] += __shfl_xor(acc[j], off);
    }
    // bias; cols >= NCLASS -> -inf
    float v[8];
#pragma unroll
    for (int j = 0; j < 8; ++j) {
        int col = c * 8 + j;
        v[j] = (col < NCLASS) ? (acc[j] + b2[col]) : -INFINITY;
    }
    // softmax over the 8 c-chunks (lane bits 0,1,2) + local 8
    float m = v[0];
#pragma unroll
    for (int j = 1; j < 8; ++j) m = fmaxf(m, v[j]);
#pragma unroll
    for (int off = 1; off <= 4; off <<= 1) m = fmaxf(m, __shfl_xor(m, off));
    float ssum = 0.f;
    float ex[8];
#pragma unroll
    for (int j = 0; j < 8; ++j) {
        ex[j] = (v[j] > -INFINITY) ? expf(v[j] - m) : 0.f;
        ssum += ex[j];
    }
#pragma unroll
    for (int off = 1; off <= 4; off <<= 1) ssum += __shfl_xor(ssum, off);
    float lse = logf(ssum);
    // write: lane's cols c*8..c*8+7, only cols < NCLASS (g==0 lanes write)
    if (g == 0) {
#pragma unroll
        for (int j = 0; j < 8; ++j) {
            int col = c * 8 + j;
            if (col < NCLASS) out[(size_t)n * NCLASS + col] = v[j] - m - lse;
        }
    }
}

extern "C" void kernel_launch(void* const* d_in, const int* in_sizes, int n_in,
                              void* d_out, int out_size, void* d_ws, size_t ws_size,
                              hipStream_t stream) {
    const float* x     = (const float*)d_in[0];
    const int*   esrc  = (const int*)d_in[1];
    const int*   edst  = (const int*)d_in[2];
    const float* ew    = (const float*)d_in[3];
    const float* eps   = (const float*)d_in[4];
    const float* W1    = (const float*)d_in[5];
    const float* b1    = (const float*)d_in[6];
    const float* W_mu  = (const float*)d_in[7];
    const float* b_mu  = (const float*)d_in[8];
    const float* W_lv  = (const float*)d_in[9];
    const float* b_lv  = (const float*)d_in[10];
    const float* W_dec = (const float*)d_in[11];
    const float* b_dec = (const float*)d_in[12];
    const float* W2    = (const float*)d_in[13];
    const float* b2    = (const float*)d_in[14];
    float* out = (float*)d_out;

    // workspace layout (counts & cursor adjacent -> single memset)
    unsigned short* support1b = (unsigned short*)d_ws;                     // 12.8M u16
    unsigned short* x1cat = support1b + (size_t)N_NODES * NHID;            // 25.6M u16
    unsigned short* S2b = x1cat + (size_t)N_NODES * 2 * NHID;              // 3.2M u16 (64-col pad)
    unsigned short* W1t    = S2b + (size_t)N_NODES * 64;
    unsigned short* W2bt   = W1t + (size_t)NHID * NFEAT;
    unsigned short* W_mulvt = W2bt + (size_t)NCLS_PAD * NFEAT;
    unsigned short* W_dect  = W_mulvt + 128 * 256;
    int*   counts   = (int*)(((size_t)(W_dect + 256 * 64) + 3) & ~(size_t)3);
    int*   cursor   = counts + N_NODES;
    int*   offsets  = cursor + N_NODES;     // N+1
    int*   blockSums    = offsets + N_NODES + 1;   // NB_SCAN
    int*   blockOffsets = blockSums + NB_SCAN;     // NB_SCAN
    int2*  edges    = (int2*)(blockOffsets + NB_SCAN);
    edges = (int2*)(((size_t)edges + 7) & ~(size_t)7);
    size_t need = (size_t)((char*)(edges + N_EDGES) - (char*)d_ws);
    if (ws_size < need) return;

    hipMemsetAsync(counts, 0, 2 * N_NODES * sizeof(int), stream);  // counts + cursor
    hist_kernel<<<(N_EDGES + 255) / 256, 256, 0, stream>>>(edst, counts);
    scan_block_sums<<<NB_SCAN, 256, 0, stream>>>(counts, blockSums);
    scan_block_offsets<<<1, 256, 0, stream>>>(blockSums, blockOffsets, offsets);
    scan_final<<<NB_SCAN, 256, 0, stream>>>(counts, blockOffsets, offsets);
    scatter_kernel<<<(N_EDGES + 255) / 256, 256, 0, stream>>>(edst, esrc, ew, offsets, cursor,
                                                              edges);

    wprep_kernel<<<800, 256, 0, stream>>>(W1, W2, W_mu, W_lv, W_dec, W1t, W2bt, W_mulvt, W_dect);
    dim3 g1((N_NODES + 127) / 128, 2);
    gemm1_mfma<<<g1, 256, 0, stream>>>(x, W1t, support1b);
    spmm1_kernel<<<N_NODES / 4, 256, 0, stream>>>(offsets, edges, support1b, b1, x1cat);
    mlp_fused<<<(N_NODES + 63) / 64, 256, 0, stream>>>(x1cat, eps, b_mu, b_lv, W_mulvt, b_dec,
                                                       W_dect, x1cat);
    gemm2_mfma<<<(N_NODES + 63) / 64, 256, 0, stream>>>(x1cat, W2bt, S2b);
    spmm2_softmax_kernel<<<N_NODES / 4, 256, 0, stream>>>(offsets, edges, S2b, b2, out);
}